// Round 9
// baseline (243.147 us; speedup 1.0000x reference)
//
#include <hip/hip_runtime.h>
#include <math.h>

#define NN 100000
#define NE 500000
#define MARGIN 0.05f

typedef short bf16x8 __attribute__((ext_vector_type(8)));
typedef float f32x4  __attribute__((ext_vector_type(4)));

static __device__ __forceinline__ unsigned short f2bf_rne(float x) {
    unsigned int u = __builtin_bit_cast(unsigned int, x);
    unsigned int r = u + 0x7fffu + ((u >> 16) & 1u);
    return (unsigned short)(r >> 16);
}
static __device__ __forceinline__ float bf2f(unsigned short b) {
    return __builtin_bit_cast(float, (unsigned int)b << 16);
}

// ---------------------------------------------------------------------------
// Kernel 0: pack merged weight Wc (128x128) into MFMA B-fragment order,
// split hi/lo bf16.  Wc[k][j] = (j<64) ? W1[k][j] : W1[128+k][j-64].
// ---------------------------------------------------------------------------
__global__ __launch_bounds__(256)
void prepack_w(const float* __restrict__ W1, unsigned short* __restrict__ WPh,
               unsigned short* __restrict__ WPl)
{
    int idx = blockIdx.x * 256 + threadIdx.x;   // 0..16383
    int e  = idx & 7;
    int l  = (idx >> 3) & 63;
    int kt = (idx >> 9) & 3;
    int jt = idx >> 11;
    int k = kt * 32 + (l >> 4) * 8 + e;
    int j = jt * 16 + (l & 15);
    float w = (j < 64) ? W1[k * 64 + j] : W1[(128 + k) * 64 + (j - 64)];
    unsigned short hb = f2bf_rne(w);
    unsigned short lb = f2bf_rne(w - bf2f(hb));
    WPh[idx] = hb;
    WPl[idx] = lb;
}

// ---------------------------------------------------------------------------
// Kernel 1: per-node projection via MFMA (mixed precision) — UNCHANGED from
// R8 (passed; logit err max ~0.0156).
// ---------------------------------------------------------------------------
__global__ __launch_bounds__(256)
void mfma_proj(const float* __restrict__ h, const unsigned short* __restrict__ WPh,
               const unsigned short* __restrict__ WPl, const float* __restrict__ b1,
               float* __restrict__ AB, int nnodes)
{
    const int t  = threadIdx.x;
    const int wv = t >> 6;            // wave 0..3
    const int l  = t & 63;
    const int lr = l & 15;            // A-row-in-tile / B-col / D-col
    const int q  = l >> 4;            // 0..3
    const int n0 = blockIdx.x * 64 + wv * 16;
    const int arow = n0 + lr;
    const bool aval = (arow < nnodes);

    bf16x8 ah[4];
    const float* hrow = h + (size_t)arow * 128;
#pragma unroll
    for (int kt = 0; kt < 4; ++kt) {
        float4 x0 = make_float4(0.f, 0.f, 0.f, 0.f);
        float4 x1 = make_float4(0.f, 0.f, 0.f, 0.f);
        if (aval) {
            x0 = *(const float4*)&hrow[kt * 32 + q * 8];
            x1 = *(const float4*)&hrow[kt * 32 + q * 8 + 4];
        }
        float xs[8] = {x0.x, x0.y, x0.z, x0.w, x1.x, x1.y, x1.z, x1.w};
        union { bf16x8 v; unsigned short u[8]; } H;
#pragma unroll
        for (int e = 0; e < 8; ++e)
            H.u[e] = (unsigned short)(__builtin_bit_cast(unsigned int, xs[e]) >> 16);
        ah[kt] = H.v;
    }

    const int drow = n0 + q * 4;

#pragma unroll
    for (int jt = 0; jt < 8; ++jt) {
        f32x4 acc = {0.f, 0.f, 0.f, 0.f};
#pragma unroll
        for (int kt = 0; kt < 4; ++kt) {
            const int fb = ((jt * 4 + kt) * 64 + l) * 8;
            bf16x8 bh = *(const bf16x8*)(WPh + fb);
            bf16x8 bl = *(const bf16x8*)(WPl + fb);
            acc = __builtin_amdgcn_mfma_f32_16x16x32_bf16(ah[kt], bh, acc, 0, 0, 0);
            acc = __builtin_amdgcn_mfma_f32_16x16x32_bf16(ah[kt], bl, acc, 0, 0, 0);
        }
        const int j = jt * 16 + lr;
        const float bias = (jt < 4) ? b1[j] : 0.f;
#pragma unroll
        for (int r = 0; r < 4; ++r) {
            int n = drow + r;
            if (n < nnodes) AB[(size_t)n * 128 + j] = acc[r] + bias;
        }
    }
}

// ---------------------------------------------------------------------------
// Kernel 2: per-edge sample — EXACT R7 hot path (proven ~32 us). The only
// addition: lane 0 appends boundary edges (|dec| < MARGIN) to a fix list.
// NO recompute code in this kernel: R8 showed the embedded branch body drove
// VGPR down to 36 and serialized the gather loads (1.5 TB/s vs 4 TB/s).
// FLAG=false variant used after the fp32 fallback projection (no fix needed).
// ---------------------------------------------------------------------------
template <bool FLAG>
__global__ __launch_bounds__(256)
void edge_sample(const float* __restrict__ AB, const float* __restrict__ W2,
                 const float* __restrict__ b2, const float* __restrict__ u,
                 const int* __restrict__ ei, float* __restrict__ out,
                 unsigned* __restrict__ counter, int* __restrict__ list, int cap)
{
    int t = threadIdx.x;
    int l = t & 15;
    int e = blockIdx.x * 16 + (t >> 4);

    int row = ei[e];
    int col = ei[NE + e];

    float4 a = *(const float4*)&AB[(size_t)row * 128 + l * 4];
    float4 b = *(const float4*)&AB[(size_t)col * 128 + 64 + l * 4];
    float4 w = *(const float4*)&W2[l * 4];

    float h0 = fmaxf(a.x + b.x, 0.f);
    float h1 = fmaxf(a.y + b.y, 0.f);
    float h2 = fmaxf(a.z + b.z, 0.f);
    float h3 = fmaxf(a.w + b.w, 0.f);

    float p = h0 * w.x + h1 * w.y + h2 * w.z + h3 * w.w;
    p += __shfl_xor(p, 1);
    p += __shfl_xor(p, 2);
    p += __shfl_xor(p, 4);
    p += __shfl_xor(p, 8);

    if (l == 0) {
        float logit = p + b2[0];
        float u0 = u[2 * e];
        float u1 = u[2 * e + 1];
        float g0 = -logf(-logf(u0));
        float g1 = -logf(-logf(u1));
        out[e]      = (logit + g1 > g0) ? 1.0f : 0.0f;  // argmax tie -> 0
        out[NE + e] = logit;
        if (FLAG) {
            float dec = (logit + g1) - g0;
            if (fabsf(dec) < MARGIN) {
                unsigned idx = atomicAdd(counter, 1u);
                if ((int)idx < cap) list[idx] = e;
            }
        }
    }
}

// ---------------------------------------------------------------------------
// Kernel 3: fp32 recompute of flagged boundary edges (~0.5-1.5% of E).
// Fixed grid (graph-capture safe); groups stride over the list. Decisions
// become exactly the fp32 decisions (same op order as the proven fallback).
// ---------------------------------------------------------------------------
__global__ __launch_bounds__(256)
void edge_fix(const float* __restrict__ h, const float* __restrict__ W1,
              const float* __restrict__ b1, const float* __restrict__ W2,
              const float* __restrict__ b2, const float* __restrict__ u,
              const int* __restrict__ ei, const unsigned* __restrict__ counter,
              const int* __restrict__ list, int cap, float* __restrict__ out)
{
    int t = threadIdx.x;
    int l = t & 15;
    int gid = blockIdx.x * 16 + (t >> 4);
    int ngroups = gridDim.x * 16;
    unsigned cnt = *counter;
    if ((int)cnt > cap) cnt = (unsigned)cap;

    for (unsigned i = gid; i < cnt; i += ngroups) {
        int e = list[i];
        int row = ei[e];
        int col = ei[NE + e];

        float4 bb = *(const float4*)&b1[l * 4];
        float a0 = bb.x, a1 = bb.y, a2 = bb.z, a3 = bb.w;
        const float* hr = h + (size_t)row * 128;
        const float* hc = h + (size_t)col * 128;

        for (int k4 = 0; k4 < 32; ++k4) {
            float4 hv = *(const float4*)&hr[k4 * 4];
#pragma unroll
            for (int kk = 0; kk < 4; ++kk) {
                float4 wr = *(const float4*)&W1[(k4 * 4 + kk) * 64 + l * 4];
                float hval = (&hv.x)[kk];
                a0 += hval * wr.x; a1 += hval * wr.y;
                a2 += hval * wr.z; a3 += hval * wr.w;
            }
        }
        for (int k4 = 0; k4 < 32; ++k4) {
            float4 hv = *(const float4*)&hc[k4 * 4];
#pragma unroll
            for (int kk = 0; kk < 4; ++kk) {
                float4 wr = *(const float4*)&W1[(128 + k4 * 4 + kk) * 64 + l * 4];
                float hval = (&hv.x)[kk];
                a0 += hval * wr.x; a1 += hval * wr.y;
                a2 += hval * wr.z; a3 += hval * wr.w;
            }
        }
        float4 w = *(const float4*)&W2[l * 4];
        float r0 = fmaxf(a0, 0.f), r1 = fmaxf(a1, 0.f);
        float r2 = fmaxf(a2, 0.f), r3 = fmaxf(a3, 0.f);
        float p = r0 * w.x + r1 * w.y + r2 * w.z + r3 * w.w;
        p += __shfl_xor(p, 1);
        p += __shfl_xor(p, 2);
        p += __shfl_xor(p, 4);
        p += __shfl_xor(p, 8);

        if (l == 0) {
            float logit = p + b2[0];
            float u0 = u[2 * e];
            float u1 = u[2 * e + 1];
            float g0 = -logf(-logf(u0));
            float g1 = -logf(-logf(u1));
            out[e]      = (logit + g1 > g0) ? 1.0f : 0.0f;
            out[NE + e] = logit;
        }
    }
}

// ---------------------------------------------------------------------------
// Mid-tier fallback: R7 fp32 node_proj (ws holds AB but not pack+list).
// ---------------------------------------------------------------------------
__global__ __launch_bounds__(256)
void node_proj(const float* __restrict__ h, const float* __restrict__ W1,
               const float* __restrict__ b1, float* __restrict__ AB, int nnodes)
{
    __shared__ float lh[64 * 132];

    const int t   = threadIdx.x;
    const int tj  = t & 15;
    const int tnf = t >> 4;
    const int n0  = blockIdx.x * 64;

#pragma unroll
    for (int i = 0; i < 8; ++i) {
        int flat = i * 256 + t;
        int nl = flat >> 5;
        int c  = flat & 31;
        int ng = n0 + nl;
        float4 v = make_float4(0.f, 0.f, 0.f, 0.f);
        if (ng < nnodes) v = *(const float4*)&h[(size_t)ng * 128 + c * 4];
        *(float4*)&lh[nl * 132 + c * 4] = v;
    }
    __syncthreads();

    const float* wa_base = W1 + tj * 4;
    const float* wb_base = W1 + 128 * 64 + tj * 4;

    float acc[4][8];
    {
        float4 bv = *(const float4*)&b1[tj * 4];
#pragma unroll
        for (int r = 0; r < 4; ++r) {
            acc[r][0] = bv.x; acc[r][1] = bv.y; acc[r][2] = bv.z; acc[r][3] = bv.w;
            acc[r][4] = 0.f;  acc[r][5] = 0.f;  acc[r][6] = 0.f;  acc[r][7] = 0.f;
        }
    }

    float4 A0[4], B0[4], A1[4], B1[4];
#pragma unroll
    for (int kk = 0; kk < 4; ++kk) {
        A0[kk] = *(const float4*)&wa_base[kk * 64];
        B0[kk] = *(const float4*)&wb_base[kk * 64];
    }

#define LOAD_W(AX, BX, K4)                                              \
    _Pragma("unroll")                                                   \
    for (int kk = 0; kk < 4; ++kk) {                                    \
        AX[kk] = *(const float4*)&wa_base[((K4) * 4 + kk) * 64];        \
        BX[kk] = *(const float4*)&wb_base[((K4) * 4 + kk) * 64];        \
    }

#define COMPUTE(AX, BX, K4)                                             \
    {                                                                   \
        float4 hv[4];                                                   \
        _Pragma("unroll")                                               \
        for (int r = 0; r < 4; ++r)                                     \
            hv[r] = *(const float4*)&lh[(tnf + 16 * r) * 132 + (K4) * 4]; \
        _Pragma("unroll")                                               \
        for (int kk = 0; kk < 4; ++kk) {                                \
            float4 wa = AX[kk], wb = BX[kk];                            \
            _Pragma("unroll")                                           \
            for (int r = 0; r < 4; ++r) {                               \
                float hk = (kk == 0) ? hv[r].x : (kk == 1) ? hv[r].y    \
                         : (kk == 2) ? hv[r].z : hv[r].w;               \
                acc[r][0] += hk * wa.x;                                 \
                acc[r][1] += hk * wa.y;                                 \
                acc[r][2] += hk * wa.z;                                 \
                acc[r][3] += hk * wa.w;                                 \
                acc[r][4] += hk * wb.x;                                 \
                acc[r][5] += hk * wb.y;                                 \
                acc[r][6] += hk * wb.z;                                 \
                acc[r][7] += hk * wb.w;                                 \
            }                                                           \
        }                                                               \
    }

#pragma unroll 1
    for (int k4 = 0; k4 < 30; k4 += 2) {
        LOAD_W(A1, B1, k4 + 1)
        COMPUTE(A0, B0, k4)
        LOAD_W(A0, B0, k4 + 2)
        COMPUTE(A1, B1, k4 + 1)
    }
    LOAD_W(A1, B1, 31)
    COMPUTE(A0, B0, 30)
    COMPUTE(A1, B1, 31)

#undef LOAD_W
#undef COMPUTE

#pragma unroll
    for (int r = 0; r < 4; ++r) {
        int ng = n0 + tnf + 16 * r;
        if (ng >= nnodes) continue;
        float* orow = AB + (size_t)ng * 128;
        *(float4*)&orow[tj * 4]      = make_float4(acc[r][0], acc[r][1], acc[r][2], acc[r][3]);
        *(float4*)&orow[64 + tj * 4] = make_float4(acc[r][4], acc[r][5], acc[r][6], acc[r][7]);
    }
}

// ---------------------------------------------------------------------------
// Low-tier fallback: direct per-edge compute (no workspace).
// ---------------------------------------------------------------------------
__global__ __launch_bounds__(256)
void edge_direct(const float* __restrict__ h, const float* __restrict__ W1,
                 const float* __restrict__ b1, const float* __restrict__ W2,
                 const float* __restrict__ b2, const float* __restrict__ u,
                 const int* __restrict__ ei, float* __restrict__ out)
{
    int t = threadIdx.x;
    int l = t & 15;
    int e = blockIdx.x * 16 + (t >> 4);

    int row = ei[e];
    int col = ei[NE + e];

    float a0 = 0.f, a1 = 0.f, a2 = 0.f, a3 = 0.f;
    const float* hr = h + (size_t)row * 128;
    const float* hc = h + (size_t)col * 128;

    for (int k4 = 0; k4 < 32; ++k4) {
        float4 hv = *(const float4*)&hr[k4 * 4];
#pragma unroll
        for (int kk = 0; kk < 4; ++kk) {
            float4 wr = *(const float4*)&W1[(k4 * 4 + kk) * 64 + l * 4];
            float hval = (&hv.x)[kk];
            a0 += hval * wr.x; a1 += hval * wr.y; a2 += hval * wr.z; a3 += hval * wr.w;
        }
    }
    for (int k4 = 0; k4 < 32; ++k4) {
        float4 hv = *(const float4*)&hc[k4 * 4];
#pragma unroll
        for (int kk = 0; kk < 4; ++kk) {
            float4 wr = *(const float4*)&W1[(128 + k4 * 4 + kk) * 64 + l * 4];
            float hval = (&hv.x)[kk];
            a0 += hval * wr.x; a1 += hval * wr.y; a2 += hval * wr.z; a3 += hval * wr.w;
        }
    }
    float4 bb = *(const float4*)&b1[l * 4];
    float4 w  = *(const float4*)&W2[l * 4];
    float h0 = fmaxf(a0 + bb.x, 0.f);
    float h1 = fmaxf(a1 + bb.y, 0.f);
    float h2 = fmaxf(a2 + bb.z, 0.f);
    float h3 = fmaxf(a3 + bb.w, 0.f);

    float p = h0 * w.x + h1 * w.y + h2 * w.z + h3 * w.w;
    p += __shfl_xor(p, 1);
    p += __shfl_xor(p, 2);
    p += __shfl_xor(p, 4);
    p += __shfl_xor(p, 8);

    if (l == 0) {
        float logit = p + b2[0];
        float u0 = u[2 * e];
        float u1 = u[2 * e + 1];
        float g0 = -logf(-logf(u0));
        float g1 = -logf(-logf(u1));
        out[e]      = (logit + g1 > g0) ? 1.0f : 0.0f;
        out[NE + e] = logit;
    }
}

extern "C" void kernel_launch(void* const* d_in, const int* in_sizes, int n_in,
                              void* d_out, int out_size, void* d_ws, size_t ws_size,
                              hipStream_t stream)
{
    const float* h  = (const float*)d_in[0];
    const float* W1 = (const float*)d_in[1];
    const float* b1 = (const float*)d_in[2];
    const float* W2 = (const float*)d_in[3];
    const float* b2 = (const float*)d_in[4];
    const float* u  = (const float*)d_in[5];
    const int*   ei = (const int*)d_in[6];
    float* out = (float*)d_out;

    const size_t ab_bytes = (size_t)NN * 128 * sizeof(float);       // 51,200,000
    const size_t wp_bytes = 2u * 16384u * sizeof(unsigned short);   // 65,536
    const size_t ctr_off  = ab_bytes + wp_bytes;                    // counter (256 B slot)
    const size_t list_off = ctr_off + 256;
    float* AB = (float*)d_ws;

    // list capacity from remaining workspace (expected flagged ~7.5K at MARGIN=0.05)
    long long rem = (long long)ws_size - (long long)list_off;
    int cap = (rem > 0) ? (int)(rem / 4) : 0;
    if (cap > 262144) cap = 262144;

    if (cap >= 16384) {
        unsigned short* WPh = (unsigned short*)((char*)d_ws + ab_bytes);
        unsigned short* WPl = WPh + 16384;
        unsigned* counter = (unsigned*)((char*)d_ws + ctr_off);
        int* list = (int*)((char*)d_ws + list_off);

        hipMemsetAsync(counter, 0, sizeof(unsigned), stream);
        prepack_w<<<64, 256, 0, stream>>>(W1, WPh, WPl);
        mfma_proj<<<(NN + 63) / 64, 256, 0, stream>>>(h, WPh, WPl, b1, AB, NN);
        edge_sample<true><<<NE / 16, 256, 0, stream>>>(AB, W2, b2, u, ei, out,
                                                       counter, list, cap);
        edge_fix<<<128, 256, 0, stream>>>(h, W1, b1, W2, b2, u, ei,
                                          counter, list, cap, out);
    } else if (ws_size >= ab_bytes) {
        node_proj<<<(NN + 63) / 64, 256, 0, stream>>>(h, W1, b1, AB, NN);
        edge_sample<false><<<NE / 16, 256, 0, stream>>>(AB, W2, b2, u, ei, out,
                                                        nullptr, nullptr, 0);
    } else {
        edge_direct<<<NE / 16, 256, 0, stream>>>(h, W1, b1, W2, b2, u, ei, out);
    }
}

// Round 10
// 210.199 us; speedup vs baseline: 1.1568x; 1.1568x over previous
//
#include <hip/hip_runtime.h>
#include <math.h>

#define NN 100000
#define NE 500000
#define MARGIN 0.05f

typedef short bf16x8 __attribute__((ext_vector_type(8)));
typedef float f32x4  __attribute__((ext_vector_type(4)));

static __device__ __forceinline__ unsigned short f2bf_rne(float x) {
    unsigned int u = __builtin_bit_cast(unsigned int, x);
    unsigned int r = u + 0x7fffu + ((u >> 16) & 1u);
    return (unsigned short)(r >> 16);
}
static __device__ __forceinline__ float bf2f(unsigned short b) {
    return __builtin_bit_cast(float, (unsigned int)b << 16);
}

// ---------------------------------------------------------------------------
// Kernel 0: pack merged weight Wc (128x128) into MFMA B-fragment order,
// split hi/lo bf16.  Wc[k][j] = (j<64) ? W1[k][j] : W1[128+k][j-64].
// ---------------------------------------------------------------------------
__global__ __launch_bounds__(256)
void prepack_w(const float* __restrict__ W1, unsigned short* __restrict__ WPh,
               unsigned short* __restrict__ WPl)
{
    int idx = blockIdx.x * 256 + threadIdx.x;   // 0..16383
    int e  = idx & 7;
    int l  = (idx >> 3) & 63;
    int kt = (idx >> 9) & 3;
    int jt = idx >> 11;
    int k = kt * 32 + (l >> 4) * 8 + e;
    int j = jt * 16 + (l & 15);
    float w = (j < 64) ? W1[k * 64 + j] : W1[(128 + k) * 64 + (j - 64)];
    unsigned short hb = f2bf_rne(w);
    unsigned short lb = f2bf_rne(w - bf2f(hb));
    WPh[idx] = hb;
    WPl[idx] = lb;
}

// ---------------------------------------------------------------------------
// Kernel 1: per-node projection via MFMA (mixed precision) — UNCHANGED from
// R8/R9 (proven; logit err max ~0.0156 < MARGIN/3).
// ---------------------------------------------------------------------------
__global__ __launch_bounds__(256)
void mfma_proj(const float* __restrict__ h, const unsigned short* __restrict__ WPh,
               const unsigned short* __restrict__ WPl, const float* __restrict__ b1,
               float* __restrict__ AB, int nnodes)
{
    const int t  = threadIdx.x;
    const int wv = t >> 6;            // wave 0..3
    const int l  = t & 63;
    const int lr = l & 15;            // A-row-in-tile / B-col / D-col
    const int q  = l >> 4;            // 0..3
    const int n0 = blockIdx.x * 64 + wv * 16;
    const int arow = n0 + lr;
    const bool aval = (arow < nnodes);

    bf16x8 ah[4];
    const float* hrow = h + (size_t)arow * 128;
#pragma unroll
    for (int kt = 0; kt < 4; ++kt) {
        float4 x0 = make_float4(0.f, 0.f, 0.f, 0.f);
        float4 x1 = make_float4(0.f, 0.f, 0.f, 0.f);
        if (aval) {
            x0 = *(const float4*)&hrow[kt * 32 + q * 8];
            x1 = *(const float4*)&hrow[kt * 32 + q * 8 + 4];
        }
        float xs[8] = {x0.x, x0.y, x0.z, x0.w, x1.x, x1.y, x1.z, x1.w};
        union { bf16x8 v; unsigned short u[8]; } H;
#pragma unroll
        for (int e = 0; e < 8; ++e)
            H.u[e] = (unsigned short)(__builtin_bit_cast(unsigned int, xs[e]) >> 16);
        ah[kt] = H.v;
    }

    const int drow = n0 + q * 4;

#pragma unroll
    for (int jt = 0; jt < 8; ++jt) {
        f32x4 acc = {0.f, 0.f, 0.f, 0.f};
#pragma unroll
        for (int kt = 0; kt < 4; ++kt) {
            const int fb = ((jt * 4 + kt) * 64 + l) * 8;
            bf16x8 bh = *(const bf16x8*)(WPh + fb);
            bf16x8 bl = *(const bf16x8*)(WPl + fb);
            acc = __builtin_amdgcn_mfma_f32_16x16x32_bf16(ah[kt], bh, acc, 0, 0, 0);
            acc = __builtin_amdgcn_mfma_f32_16x16x32_bf16(ah[kt], bl, acc, 0, 0, 0);
        }
        const int j = jt * 16 + lr;
        const float bias = (jt < 4) ? b1[j] : 0.f;
#pragma unroll
        for (int r = 0; r < 4; ++r) {
            int n = drow + r;
            if (n < nnodes) AB[(size_t)n * 128 + j] = acc[r] + bias;
        }
    }
}

// ---------------------------------------------------------------------------
// Kernel 2: per-edge sample — VERBATIM R7/R1 hot path (proven 31-33 us).
// NOTHING may be added to this kernel: R8 (embedded recompute -> VGPR 36,
// 88us) and R9 (template+atomic flag -> VGPR 12, 136us) both showed the
// compiler minimizes VGPRs across all paths, destroying the gather MLP.
// ---------------------------------------------------------------------------
__global__ __launch_bounds__(256)
void edge_sample(const float* __restrict__ AB, const float* __restrict__ W2,
                 const float* __restrict__ b2, const float* __restrict__ u,
                 const int* __restrict__ ei, float* __restrict__ out)
{
    int t = threadIdx.x;
    int l = t & 15;
    int e = blockIdx.x * 16 + (t >> 4);

    int row = ei[e];
    int col = ei[NE + e];

    float4 a = *(const float4*)&AB[(size_t)row * 128 + l * 4];
    float4 b = *(const float4*)&AB[(size_t)col * 128 + 64 + l * 4];
    float4 w = *(const float4*)&W2[l * 4];

    float h0 = fmaxf(a.x + b.x, 0.f);
    float h1 = fmaxf(a.y + b.y, 0.f);
    float h2 = fmaxf(a.z + b.z, 0.f);
    float h3 = fmaxf(a.w + b.w, 0.f);

    float p = h0 * w.x + h1 * w.y + h2 * w.z + h3 * w.w;
    p += __shfl_xor(p, 1);
    p += __shfl_xor(p, 2);
    p += __shfl_xor(p, 4);
    p += __shfl_xor(p, 8);

    if (l == 0) {
        float logit = p + b2[0];
        float u0 = u[2 * e];
        float u1 = u[2 * e + 1];
        float g0 = -logf(-logf(u0));
        float g1 = -logf(-logf(u1));
        out[e]      = (logit + g1 > g0) ? 1.0f : 0.0f;  // argmax tie -> 0
        out[NE + e] = logit;
    }
}

// ---------------------------------------------------------------------------
// Kernel 3: boundary check + fp32 recompute, fully decoupled from the hot
// kernel. Re-derives dec from out[NE+e] (fast-path logit) and u; edges with
// |dec| < MARGIN get an exact fp32 recompute (same op order as the proven
// fp32 fallback) overwriting out. No atomics/list -> deterministic.
// Grid-stride 16-lane groups; ~1-2% of edges take the slow branch.
// ---------------------------------------------------------------------------
__global__ __launch_bounds__(256)
void edge_check(const float* __restrict__ h, const float* __restrict__ W1,
                const float* __restrict__ b1, const float* __restrict__ W2,
                const float* __restrict__ b2, const float* __restrict__ u,
                const int* __restrict__ ei, float* __restrict__ out)
{
    int t = threadIdx.x;
    int l = t & 15;
    int gid = blockIdx.x * 16 + (t >> 4);
    int ngroups = gridDim.x * 16;

    for (int e = gid; e < NE; e += ngroups) {
        float logit_f = out[NE + e];
        float u0 = u[2 * e];
        float u1 = u[2 * e + 1];
        float g0 = -logf(-logf(u0));
        float g1 = -logf(-logf(u1));
        float dec = (logit_f + g1) - g0;
        if (fabsf(dec) >= MARGIN) continue;

        int row = ei[e];
        int col = ei[NE + e];

        float4 bb = *(const float4*)&b1[l * 4];
        float a0 = bb.x, a1 = bb.y, a2 = bb.z, a3 = bb.w;
        const float* hr = h + (size_t)row * 128;
        const float* hc = h + (size_t)col * 128;

        for (int k4 = 0; k4 < 32; ++k4) {
            float4 hv = *(const float4*)&hr[k4 * 4];
#pragma unroll
            for (int kk = 0; kk < 4; ++kk) {
                float4 wr = *(const float4*)&W1[(k4 * 4 + kk) * 64 + l * 4];
                float hval = (&hv.x)[kk];
                a0 += hval * wr.x; a1 += hval * wr.y;
                a2 += hval * wr.z; a3 += hval * wr.w;
            }
        }
        for (int k4 = 0; k4 < 32; ++k4) {
            float4 hv = *(const float4*)&hc[k4 * 4];
#pragma unroll
            for (int kk = 0; kk < 4; ++kk) {
                float4 wr = *(const float4*)&W1[(128 + k4 * 4 + kk) * 64 + l * 4];
                float hval = (&hv.x)[kk];
                a0 += hval * wr.x; a1 += hval * wr.y;
                a2 += hval * wr.z; a3 += hval * wr.w;
            }
        }
        float4 w = *(const float4*)&W2[l * 4];
        float r0 = fmaxf(a0, 0.f), r1 = fmaxf(a1, 0.f);
        float r2 = fmaxf(a2, 0.f), r3 = fmaxf(a3, 0.f);
        float p = r0 * w.x + r1 * w.y + r2 * w.z + r3 * w.w;
        p += __shfl_xor(p, 1);
        p += __shfl_xor(p, 2);
        p += __shfl_xor(p, 4);
        p += __shfl_xor(p, 8);

        if (l == 0) {
            float logit = p + b2[0];
            out[e]      = (logit + g1 > g0) ? 1.0f : 0.0f;
            out[NE + e] = logit;
        }
    }
}

// ---------------------------------------------------------------------------
// Mid-tier fallback: R7 fp32 node_proj (ws holds AB but not the W pack).
// ---------------------------------------------------------------------------
__global__ __launch_bounds__(256)
void node_proj(const float* __restrict__ h, const float* __restrict__ W1,
               const float* __restrict__ b1, float* __restrict__ AB, int nnodes)
{
    __shared__ float lh[64 * 132];

    const int t   = threadIdx.x;
    const int tj  = t & 15;
    const int tnf = t >> 4;
    const int n0  = blockIdx.x * 64;

#pragma unroll
    for (int i = 0; i < 8; ++i) {
        int flat = i * 256 + t;
        int nl = flat >> 5;
        int c  = flat & 31;
        int ng = n0 + nl;
        float4 v = make_float4(0.f, 0.f, 0.f, 0.f);
        if (ng < nnodes) v = *(const float4*)&h[(size_t)ng * 128 + c * 4];
        *(float4*)&lh[nl * 132 + c * 4] = v;
    }
    __syncthreads();

    const float* wa_base = W1 + tj * 4;
    const float* wb_base = W1 + 128 * 64 + tj * 4;

    float acc[4][8];
    {
        float4 bv = *(const float4*)&b1[tj * 4];
#pragma unroll
        for (int r = 0; r < 4; ++r) {
            acc[r][0] = bv.x; acc[r][1] = bv.y; acc[r][2] = bv.z; acc[r][3] = bv.w;
            acc[r][4] = 0.f;  acc[r][5] = 0.f;  acc[r][6] = 0.f;  acc[r][7] = 0.f;
        }
    }

    float4 A0[4], B0[4], A1[4], B1[4];
#pragma unroll
    for (int kk = 0; kk < 4; ++kk) {
        A0[kk] = *(const float4*)&wa_base[kk * 64];
        B0[kk] = *(const float4*)&wb_base[kk * 64];
    }

#define LOAD_W(AX, BX, K4)                                              \
    _Pragma("unroll")                                                   \
    for (int kk = 0; kk < 4; ++kk) {                                    \
        AX[kk] = *(const float4*)&wa_base[((K4) * 4 + kk) * 64];        \
        BX[kk] = *(const float4*)&wb_base[((K4) * 4 + kk) * 64];        \
    }

#define COMPUTE(AX, BX, K4)                                             \
    {                                                                   \
        float4 hv[4];                                                   \
        _Pragma("unroll")                                               \
        for (int r = 0; r < 4; ++r)                                     \
            hv[r] = *(const float4*)&lh[(tnf + 16 * r) * 132 + (K4) * 4]; \
        _Pragma("unroll")                                               \
        for (int kk = 0; kk < 4; ++kk) {                                \
            float4 wa = AX[kk], wb = BX[kk];                            \
            _Pragma("unroll")                                           \
            for (int r = 0; r < 4; ++r) {                               \
                float hk = (kk == 0) ? hv[r].x : (kk == 1) ? hv[r].y    \
                         : (kk == 2) ? hv[r].z : hv[r].w;               \
                acc[r][0] += hk * wa.x;                                 \
                acc[r][1] += hk * wa.y;                                 \
                acc[r][2] += hk * wa.z;                                 \
                acc[r][3] += hk * wa.w;                                 \
                acc[r][4] += hk * wb.x;                                 \
                acc[r][5] += hk * wb.y;                                 \
                acc[r][6] += hk * wb.z;                                 \
                acc[r][7] += hk * wb.w;                                 \
            }                                                           \
        }                                                               \
    }

#pragma unroll 1
    for (int k4 = 0; k4 < 30; k4 += 2) {
        LOAD_W(A1, B1, k4 + 1)
        COMPUTE(A0, B0, k4)
        LOAD_W(A0, B0, k4 + 2)
        COMPUTE(A1, B1, k4 + 1)
    }
    LOAD_W(A1, B1, 31)
    COMPUTE(A0, B0, 30)
    COMPUTE(A1, B1, 31)

#undef LOAD_W
#undef COMPUTE

#pragma unroll
    for (int r = 0; r < 4; ++r) {
        int ng = n0 + tnf + 16 * r;
        if (ng >= nnodes) continue;
        float* orow = AB + (size_t)ng * 128;
        *(float4*)&orow[tj * 4]      = make_float4(acc[r][0], acc[r][1], acc[r][2], acc[r][3]);
        *(float4*)&orow[64 + tj * 4] = make_float4(acc[r][4], acc[r][5], acc[r][6], acc[r][7]);
    }
}

// ---------------------------------------------------------------------------
// Low-tier fallback: direct per-edge compute (no workspace).
// ---------------------------------------------------------------------------
__global__ __launch_bounds__(256)
void edge_direct(const float* __restrict__ h, const float* __restrict__ W1,
                 const float* __restrict__ b1, const float* __restrict__ W2,
                 const float* __restrict__ b2, const float* __restrict__ u,
                 const int* __restrict__ ei, float* __restrict__ out)
{
    int t = threadIdx.x;
    int l = t & 15;
    int e = blockIdx.x * 16 + (t >> 4);

    int row = ei[e];
    int col = ei[NE + e];

    float a0 = 0.f, a1 = 0.f, a2 = 0.f, a3 = 0.f;
    const float* hr = h + (size_t)row * 128;
    const float* hc = h + (size_t)col * 128;

    for (int k4 = 0; k4 < 32; ++k4) {
        float4 hv = *(const float4*)&hr[k4 * 4];
#pragma unroll
        for (int kk = 0; kk < 4; ++kk) {
            float4 wr = *(const float4*)&W1[(k4 * 4 + kk) * 64 + l * 4];
            float hval = (&hv.x)[kk];
            a0 += hval * wr.x; a1 += hval * wr.y; a2 += hval * wr.z; a3 += hval * wr.w;
        }
    }
    for (int k4 = 0; k4 < 32; ++k4) {
        float4 hv = *(const float4*)&hc[k4 * 4];
#pragma unroll
        for (int kk = 0; kk < 4; ++kk) {
            float4 wr = *(const float4*)&W1[(128 + k4 * 4 + kk) * 64 + l * 4];
            float hval = (&hv.x)[kk];
            a0 += hval * wr.x; a1 += hval * wr.y; a2 += hval * wr.z; a3 += hval * wr.w;
        }
    }
    float4 bb = *(const float4*)&b1[l * 4];
    float4 w  = *(const float4*)&W2[l * 4];
    float h0 = fmaxf(a0 + bb.x, 0.f);
    float h1 = fmaxf(a1 + bb.y, 0.f);
    float h2 = fmaxf(a2 + bb.z, 0.f);
    float h3 = fmaxf(a3 + bb.w, 0.f);

    float p = h0 * w.x + h1 * w.y + h2 * w.z + h3 * w.w;
    p += __shfl_xor(p, 1);
    p += __shfl_xor(p, 2);
    p += __shfl_xor(p, 4);
    p += __shfl_xor(p, 8);

    if (l == 0) {
        float logit = p + b2[0];
        float u0 = u[2 * e];
        float u1 = u[2 * e + 1];
        float g0 = -logf(-logf(u0));
        float g1 = -logf(-logf(u1));
        out[e]      = (logit + g1 > g0) ? 1.0f : 0.0f;
        out[NE + e] = logit;
    }
}

extern "C" void kernel_launch(void* const* d_in, const int* in_sizes, int n_in,
                              void* d_out, int out_size, void* d_ws, size_t ws_size,
                              hipStream_t stream)
{
    const float* h  = (const float*)d_in[0];
    const float* W1 = (const float*)d_in[1];
    const float* b1 = (const float*)d_in[2];
    const float* W2 = (const float*)d_in[3];
    const float* b2 = (const float*)d_in[4];
    const float* u  = (const float*)d_in[5];
    const int*   ei = (const int*)d_in[6];
    float* out = (float*)d_out;

    const size_t ab_bytes = (size_t)NN * 128 * sizeof(float);       // 51,200,000
    const size_t wp_bytes = 2u * 16384u * sizeof(unsigned short);   // 65,536
    float* AB = (float*)d_ws;

    if (ws_size >= ab_bytes + wp_bytes) {
        unsigned short* WPh = (unsigned short*)((char*)d_ws + ab_bytes);
        unsigned short* WPl = WPh + 16384;
        prepack_w<<<64, 256, 0, stream>>>(W1, WPh, WPl);
        mfma_proj<<<(NN + 63) / 64, 256, 0, stream>>>(h, WPh, WPl, b1, AB, NN);
        edge_sample<<<NE / 16, 256, 0, stream>>>(AB, W2, b2, u, ei, out);
        edge_check<<<4096, 256, 0, stream>>>(h, W1, b1, W2, b2, u, ei, out);
    } else if (ws_size >= ab_bytes) {
        node_proj<<<(NN + 63) / 64, 256, 0, stream>>>(h, W1, b1, AB, NN);
        edge_sample<<<NE / 16, 256, 0, stream>>>(AB, W2, b2, u, ei, out);
    } else {
        edge_direct<<<NE / 16, 256, 0, stream>>>(h, W1, b1, W2, b2, u, ei, out);
    }
}

// Round 11
// 136.878 us; speedup vs baseline: 1.7764x; 1.5357x over previous
//
#include <hip/hip_runtime.h>
#include <math.h>

#define NN 100000
#define NE 500000
#define MARGIN 0.05f
#define FIXCAP 2048

typedef short bf16x8 __attribute__((ext_vector_type(8)));
typedef float f32x4  __attribute__((ext_vector_type(4)));

static __device__ __forceinline__ unsigned short f2bf_rne(float x) {
    unsigned int u = __builtin_bit_cast(unsigned int, x);
    unsigned int r = u + 0x7fffu + ((u >> 16) & 1u);
    return (unsigned short)(r >> 16);
}
static __device__ __forceinline__ float bf2f(unsigned short b) {
    return __builtin_bit_cast(float, (unsigned int)b << 16);
}

// ---------------------------------------------------------------------------
// Kernel 0: pack merged weight Wc (128x128) into MFMA B-fragment order,
// split hi/lo bf16.  Wc[k][j] = (j<64) ? W1[k][j] : W1[128+k][j-64].
// ---------------------------------------------------------------------------
__global__ __launch_bounds__(256)
void prepack_w(const float* __restrict__ W1, unsigned short* __restrict__ WPh,
               unsigned short* __restrict__ WPl)
{
    int idx = blockIdx.x * 256 + threadIdx.x;   // 0..16383
    int e  = idx & 7;
    int l  = (idx >> 3) & 63;
    int kt = (idx >> 9) & 3;
    int jt = idx >> 11;
    int k = kt * 32 + (l >> 4) * 8 + e;
    int j = jt * 16 + (l & 15);
    float w = (j < 64) ? W1[k * 64 + j] : W1[(128 + k) * 64 + (j - 64)];
    unsigned short hb = f2bf_rne(w);
    unsigned short lb = f2bf_rne(w - bf2f(hb));
    WPh[idx] = hb;
    WPl[idx] = lb;
}

// ---------------------------------------------------------------------------
// Kernel 1: per-node projection via MFMA (mixed precision) — UNCHANGED from
// R8-R10 (proven; logit err max ~0.0156 < MARGIN/3).
// ---------------------------------------------------------------------------
__global__ __launch_bounds__(256)
void mfma_proj(const float* __restrict__ h, const unsigned short* __restrict__ WPh,
               const unsigned short* __restrict__ WPl, const float* __restrict__ b1,
               float* __restrict__ AB, int nnodes)
{
    const int t  = threadIdx.x;
    const int wv = t >> 6;            // wave 0..3
    const int l  = t & 63;
    const int lr = l & 15;            // A-row-in-tile / B-col / D-col
    const int q  = l >> 4;            // 0..3
    const int n0 = blockIdx.x * 64 + wv * 16;
    const int arow = n0 + lr;
    const bool aval = (arow < nnodes);

    bf16x8 ah[4];
    const float* hrow = h + (size_t)arow * 128;
#pragma unroll
    for (int kt = 0; kt < 4; ++kt) {
        float4 x0 = make_float4(0.f, 0.f, 0.f, 0.f);
        float4 x1 = make_float4(0.f, 0.f, 0.f, 0.f);
        if (aval) {
            x0 = *(const float4*)&hrow[kt * 32 + q * 8];
            x1 = *(const float4*)&hrow[kt * 32 + q * 8 + 4];
        }
        float xs[8] = {x0.x, x0.y, x0.z, x0.w, x1.x, x1.y, x1.z, x1.w};
        union { bf16x8 v; unsigned short u[8]; } H;
#pragma unroll
        for (int e = 0; e < 8; ++e)
            H.u[e] = (unsigned short)(__builtin_bit_cast(unsigned int, xs[e]) >> 16);
        ah[kt] = H.v;
    }

    const int drow = n0 + q * 4;

#pragma unroll
    for (int jt = 0; jt < 8; ++jt) {
        f32x4 acc = {0.f, 0.f, 0.f, 0.f};
#pragma unroll
        for (int kt = 0; kt < 4; ++kt) {
            const int fb = ((jt * 4 + kt) * 64 + l) * 8;
            bf16x8 bh = *(const bf16x8*)(WPh + fb);
            bf16x8 bl = *(const bf16x8*)(WPl + fb);
            acc = __builtin_amdgcn_mfma_f32_16x16x32_bf16(ah[kt], bh, acc, 0, 0, 0);
            acc = __builtin_amdgcn_mfma_f32_16x16x32_bf16(ah[kt], bl, acc, 0, 0, 0);
        }
        const int j = jt * 16 + lr;
        const float bias = (jt < 4) ? b1[j] : 0.f;
#pragma unroll
        for (int r = 0; r < 4; ++r) {
            int n = drow + r;
            if (n < nnodes) AB[(size_t)n * 128 + j] = acc[r] + bias;
        }
    }
}

// ---------------------------------------------------------------------------
// Kernel 2: per-edge sample — VERBATIM R7/R1 hot path (proven 31-33 us).
// NOTHING may be added to this kernel: R8 (embedded recompute -> VGPR 36,
// 88us) and R9 (template+atomic flag -> VGPR 12, 136us) both showed the
// compiler minimizes VGPRs across all paths, destroying the gather MLP.
// ---------------------------------------------------------------------------
__global__ __launch_bounds__(256)
void edge_sample(const float* __restrict__ AB, const float* __restrict__ W2,
                 const float* __restrict__ b2, const float* __restrict__ u,
                 const int* __restrict__ ei, float* __restrict__ out)
{
    int t = threadIdx.x;
    int l = t & 15;
    int e = blockIdx.x * 16 + (t >> 4);

    int row = ei[e];
    int col = ei[NE + e];

    float4 a = *(const float4*)&AB[(size_t)row * 128 + l * 4];
    float4 b = *(const float4*)&AB[(size_t)col * 128 + 64 + l * 4];
    float4 w = *(const float4*)&W2[l * 4];

    float h0 = fmaxf(a.x + b.x, 0.f);
    float h1 = fmaxf(a.y + b.y, 0.f);
    float h2 = fmaxf(a.z + b.z, 0.f);
    float h3 = fmaxf(a.w + b.w, 0.f);

    float p = h0 * w.x + h1 * w.y + h2 * w.z + h3 * w.w;
    p += __shfl_xor(p, 1);
    p += __shfl_xor(p, 2);
    p += __shfl_xor(p, 4);
    p += __shfl_xor(p, 8);

    if (l == 0) {
        float logit = p + b2[0];
        float u0 = u[2 * e];
        float u1 = u[2 * e + 1];
        float g0 = -logf(-logf(u0));
        float g1 = -logf(-logf(u1));
        out[e]      = (logit + g1 > g0) ? 1.0f : 0.0f;  // argmax tie -> 0
        out[NE + e] = logit;
    }
}

// ---------------------------------------------------------------------------
// Kernel 3: boundary check v2 — scan + block-local wave-parallel recompute.
// R10's version was latency-serial (VGPR 36 -> 1 load in flight -> ~40us per
// flagged wave -> 152us dispatch). v2:
//   Phase 1: thread = edge. Flag |dec| < MARGIN into per-block LDS list.
//   Phase 2: wave = flagged edge. lane l = output column l (W1 reads
//            coalesced 256B/wave); k-loop unrolled x4 with named loads ->
//            ~40 loads in flight. Butterfly-reduce 64 lanes; lane 0 writes.
// Exact fp32, per-column k-ascending sum order (same as proven edge_direct).
// Deterministic: list order irrelevant (distinct e -> distinct out slots).
// ---------------------------------------------------------------------------
__global__ __launch_bounds__(256)
void edge_check(const float* __restrict__ h, const float* __restrict__ W1,
                const float* __restrict__ b1, const float* __restrict__ W2,
                const float* __restrict__ b2, const float* __restrict__ u,
                const int* __restrict__ ei, float* __restrict__ out)
{
    __shared__ unsigned lcnt;
    __shared__ int llist[FIXCAP];

    const int t = threadIdx.x;
    if (t == 0) lcnt = 0;
    __syncthreads();

    // ---- phase 1: scan (1 edge per thread) ----
    int e0 = blockIdx.x * 256 + t;
    if (e0 < NE) {
        float logit = out[NE + e0];
        float g0 = -logf(-logf(u[2 * e0]));
        float g1 = -logf(-logf(u[2 * e0 + 1]));
        if (fabsf((logit + g1) - g0) < MARGIN) {
            unsigned i = atomicAdd(&lcnt, 1u);
            if (i < FIXCAP) llist[i] = e0;
        }
    }
    __syncthreads();

    unsigned cnt = lcnt;
    if (cnt > FIXCAP) cnt = FIXCAP;
    if (cnt == 0) return;

    const int wid = t >> 6;          // wave 0..3
    const int l   = t & 63;          // lane = output column

    for (unsigned i = wid; i < cnt; i += 4) {
        int e = llist[i];
        int row = ei[e];
        int col = ei[NE + e];

        const float* hr = h + (size_t)row * 128;
        const float* hc = h + (size_t)col * 128;
        const float* Wr = W1 + l;              // column l, row stride 64
        float acc = b1[l];

        // first half: k = 0..127 over h[row], W1 rows 0..127
#pragma unroll 4
        for (int kc = 0; kc < 16; ++kc) {
            float4 ha = *(const float4*)&hr[kc * 8];
            float4 hb = *(const float4*)&hr[kc * 8 + 4];
            float w0 = Wr[(kc * 8 + 0) * 64];
            float w1 = Wr[(kc * 8 + 1) * 64];
            float w2 = Wr[(kc * 8 + 2) * 64];
            float w3 = Wr[(kc * 8 + 3) * 64];
            float w4 = Wr[(kc * 8 + 4) * 64];
            float w5 = Wr[(kc * 8 + 5) * 64];
            float w6 = Wr[(kc * 8 + 6) * 64];
            float w7 = Wr[(kc * 8 + 7) * 64];
            acc += ha.x * w0; acc += ha.y * w1; acc += ha.z * w2; acc += ha.w * w3;
            acc += hb.x * w4; acc += hb.y * w5; acc += hb.z * w6; acc += hb.w * w7;
        }
        // second half: k = 0..127 over h[col], W1 rows 128..255
        const float* Wc2 = Wr + 128 * 64;
#pragma unroll 4
        for (int kc = 0; kc < 16; ++kc) {
            float4 ha = *(const float4*)&hc[kc * 8];
            float4 hb = *(const float4*)&hc[kc * 8 + 4];
            float w0 = Wc2[(kc * 8 + 0) * 64];
            float w1 = Wc2[(kc * 8 + 1) * 64];
            float w2 = Wc2[(kc * 8 + 2) * 64];
            float w3 = Wc2[(kc * 8 + 3) * 64];
            float w4 = Wc2[(kc * 8 + 4) * 64];
            float w5 = Wc2[(kc * 8 + 5) * 64];
            float w6 = Wc2[(kc * 8 + 6) * 64];
            float w7 = Wc2[(kc * 8 + 7) * 64];
            acc += ha.x * w0; acc += ha.y * w1; acc += ha.z * w2; acc += ha.w * w3;
            acc += hb.x * w4; acc += hb.y * w5; acc += hb.z * w6; acc += hb.w * w7;
        }

        float p = fmaxf(acc, 0.f) * W2[l];
        p += __shfl_xor(p, 1);
        p += __shfl_xor(p, 2);
        p += __shfl_xor(p, 4);
        p += __shfl_xor(p, 8);
        p += __shfl_xor(p, 16);
        p += __shfl_xor(p, 32);

        if (l == 0) {
            float logit = p + b2[0];
            float g0 = -logf(-logf(u[2 * e]));
            float g1 = -logf(-logf(u[2 * e + 1]));
            out[e]      = (logit + g1 > g0) ? 1.0f : 0.0f;
            out[NE + e] = logit;
        }
    }
}

// ---------------------------------------------------------------------------
// Mid-tier fallback: R7 fp32 node_proj (ws holds AB but not the W pack).
// ---------------------------------------------------------------------------
__global__ __launch_bounds__(256)
void node_proj(const float* __restrict__ h, const float* __restrict__ W1,
               const float* __restrict__ b1, float* __restrict__ AB, int nnodes)
{
    __shared__ float lh[64 * 132];

    const int t   = threadIdx.x;
    const int tj  = t & 15;
    const int tnf = t >> 4;
    const int n0  = blockIdx.x * 64;

#pragma unroll
    for (int i = 0; i < 8; ++i) {
        int flat = i * 256 + t;
        int nl = flat >> 5;
        int c  = flat & 31;
        int ng = n0 + nl;
        float4 v = make_float4(0.f, 0.f, 0.f, 0.f);
        if (ng < nnodes) v = *(const float4*)&h[(size_t)ng * 128 + c * 4];
        *(float4*)&lh[nl * 132 + c * 4] = v;
    }
    __syncthreads();

    const float* wa_base = W1 + tj * 4;
    const float* wb_base = W1 + 128 * 64 + tj * 4;

    float acc[4][8];
    {
        float4 bv = *(const float4*)&b1[tj * 4];
#pragma unroll
        for (int r = 0; r < 4; ++r) {
            acc[r][0] = bv.x; acc[r][1] = bv.y; acc[r][2] = bv.z; acc[r][3] = bv.w;
            acc[r][4] = 0.f;  acc[r][5] = 0.f;  acc[r][6] = 0.f;  acc[r][7] = 0.f;
        }
    }

    float4 A0[4], B0[4], A1[4], B1[4];
#pragma unroll
    for (int kk = 0; kk < 4; ++kk) {
        A0[kk] = *(const float4*)&wa_base[kk * 64];
        B0[kk] = *(const float4*)&wb_base[kk * 64];
    }

#define LOAD_W(AX, BX, K4)                                              \
    _Pragma("unroll")                                                   \
    for (int kk = 0; kk < 4; ++kk) {                                    \
        AX[kk] = *(const float4*)&wa_base[((K4) * 4 + kk) * 64];        \
        BX[kk] = *(const float4*)&wb_base[((K4) * 4 + kk) * 64];        \
    }

#define COMPUTE(AX, BX, K4)                                             \
    {                                                                   \
        float4 hv[4];                                                   \
        _Pragma("unroll")                                               \
        for (int r = 0; r < 4; ++r)                                     \
            hv[r] = *(const float4*)&lh[(tnf + 16 * r) * 132 + (K4) * 4]; \
        _Pragma("unroll")                                               \
        for (int kk = 0; kk < 4; ++kk) {                                \
            float4 wa = AX[kk], wb = BX[kk];                            \
            _Pragma("unroll")                                           \
            for (int r = 0; r < 4; ++r) {                               \
                float hk = (kk == 0) ? hv[r].x : (kk == 1) ? hv[r].y    \
                         : (kk == 2) ? hv[r].z : hv[r].w;               \
                acc[r][0] += hk * wa.x;                                 \
                acc[r][1] += hk * wa.y;                                 \
                acc[r][2] += hk * wa.z;                                 \
                acc[r][3] += hk * wa.w;                                 \
                acc[r][4] += hk * wb.x;                                 \
                acc[r][5] += hk * wb.y;                                 \
                acc[r][6] += hk * wb.z;                                 \
                acc[r][7] += hk * wb.w;                                 \
            }                                                           \
        }                                                               \
    }

#pragma unroll 1
    for (int k4 = 0; k4 < 30; k4 += 2) {
        LOAD_W(A1, B1, k4 + 1)
        COMPUTE(A0, B0, k4)
        LOAD_W(A0, B0, k4 + 2)
        COMPUTE(A1, B1, k4 + 1)
    }
    LOAD_W(A1, B1, 31)
    COMPUTE(A0, B0, 30)
    COMPUTE(A1, B1, 31)

#undef LOAD_W
#undef COMPUTE

#pragma unroll
    for (int r = 0; r < 4; ++r) {
        int ng = n0 + tnf + 16 * r;
        if (ng >= nnodes) continue;
        float* orow = AB + (size_t)ng * 128;
        *(float4*)&orow[tj * 4]      = make_float4(acc[r][0], acc[r][1], acc[r][2], acc[r][3]);
        *(float4*)&orow[64 + tj * 4] = make_float4(acc[r][4], acc[r][5], acc[r][6], acc[r][7]);
    }
}

// ---------------------------------------------------------------------------
// Low-tier fallback: direct per-edge compute (no workspace).
// ---------------------------------------------------------------------------
__global__ __launch_bounds__(256)
void edge_direct(const float* __restrict__ h, const float* __restrict__ W1,
                 const float* __restrict__ b1, const float* __restrict__ W2,
                 const float* __restrict__ b2, const float* __restrict__ u,
                 const int* __restrict__ ei, float* __restrict__ out)
{
    int t = threadIdx.x;
    int l = t & 15;
    int e = blockIdx.x * 16 + (t >> 4);

    int row = ei[e];
    int col = ei[NE + e];

    float a0 = 0.f, a1 = 0.f, a2 = 0.f, a3 = 0.f;
    const float* hr = h + (size_t)row * 128;
    const float* hc = h + (size_t)col * 128;

    for (int k4 = 0; k4 < 32; ++k4) {
        float4 hv = *(const float4*)&hr[k4 * 4];
#pragma unroll
        for (int kk = 0; kk < 4; ++kk) {
            float4 wr = *(const float4*)&W1[(k4 * 4 + kk) * 64 + l * 4];
            float hval = (&hv.x)[kk];
            a0 += hval * wr.x; a1 += hval * wr.y; a2 += hval * wr.z; a3 += hval * wr.w;
        }
    }
    for (int k4 = 0; k4 < 32; ++k4) {
        float4 hv = *(const float4*)&hc[k4 * 4];
#pragma unroll
        for (int kk = 0; kk < 4; ++kk) {
            float4 wr = *(const float4*)&W1[(128 + k4 * 4 + kk) * 64 + l * 4];
            float hval = (&hv.x)[kk];
            a0 += hval * wr.x; a1 += hval * wr.y; a2 += hval * wr.z; a3 += hval * wr.w;
        }
    }
    float4 bb = *(const float4*)&b1[l * 4];
    float4 w  = *(const float4*)&W2[l * 4];
    float h0 = fmaxf(a0 + bb.x, 0.f);
    float h1 = fmaxf(a1 + bb.y, 0.f);
    float h2 = fmaxf(a2 + bb.z, 0.f);
    float h3 = fmaxf(a3 + bb.w, 0.f);

    float p = h0 * w.x + h1 * w.y + h2 * w.z + h3 * w.w;
    p += __shfl_xor(p, 1);
    p += __shfl_xor(p, 2);
    p += __shfl_xor(p, 4);
    p += __shfl_xor(p, 8);

    if (l == 0) {
        float logit = p + b2[0];
        float u0 = u[2 * e];
        float u1 = u[2 * e + 1];
        float g0 = -logf(-logf(u0));
        float g1 = -logf(-logf(u1));
        out[e]      = (logit + g1 > g0) ? 1.0f : 0.0f;
        out[NE + e] = logit;
    }
}

extern "C" void kernel_launch(void* const* d_in, const int* in_sizes, int n_in,
                              void* d_out, int out_size, void* d_ws, size_t ws_size,
                              hipStream_t stream)
{
    const float* h  = (const float*)d_in[0];
    const float* W1 = (const float*)d_in[1];
    const float* b1 = (const float*)d_in[2];
    const float* W2 = (const float*)d_in[3];
    const float* b2 = (const float*)d_in[4];
    const float* u  = (const float*)d_in[5];
    const int*   ei = (const int*)d_in[6];
    float* out = (float*)d_out;

    const size_t ab_bytes = (size_t)NN * 128 * sizeof(float);       // 51,200,000
    const size_t wp_bytes = 2u * 16384u * sizeof(unsigned short);   // 65,536
    float* AB = (float*)d_ws;

    if (ws_size >= ab_bytes + wp_bytes) {
        unsigned short* WPh = (unsigned short*)((char*)d_ws + ab_bytes);
        unsigned short* WPl = WPh + 16384;
        prepack_w<<<64, 256, 0, stream>>>(W1, WPh, WPl);
        mfma_proj<<<(NN + 63) / 64, 256, 0, stream>>>(h, WPh, WPl, b1, AB, NN);
        edge_sample<<<NE / 16, 256, 0, stream>>>(AB, W2, b2, u, ei, out);
        edge_check<<<(NE + 255) / 256, 256, 0, stream>>>(h, W1, b1, W2, b2, u, ei, out);
    } else if (ws_size >= ab_bytes) {
        node_proj<<<(NN + 63) / 64, 256, 0, stream>>>(h, W1, b1, AB, NN);
        edge_sample<<<NE / 16, 256, 0, stream>>>(AB, W2, b2, u, ei, out);
    } else {
        edge_direct<<<NE / 16, 256, 0, stream>>>(h, W1, b1, W2, b2, u, ei, out);
    }
}